// Round 9
// baseline (511227.588 us; speedup 1.0000x reference)
//
#include <hip/hip_runtime.h>
#include <hip/hip_fp16.h>
#include <math.h>

typedef unsigned int  uint32;
typedef unsigned short u16;

#define NWG 68          // wg 0-3: GRU quarter-WGs; wg 4-67: 64 helper WGs
#define NTH 256         // 256-thr block => 256-VGPR RA budget (empirical law: 65536/NTH)

// workspace layout (bytes)
#define OFF_MB1  256u                         // mini-barrier count
#define OFF_MB2  384u                         // mini-barrier release
#define OFF_HB   512u                         // h exchange: 2 bufs x 256 u16 = 1 KB
#define OFF_XP   2048u                        // xp [256][768] f32 (b_ih + b_hh[r,z] folded)
#define OFF_XC   (OFF_XP + 256u*768u*4u)      // seq / Xr [256][256] f32
#define OFF_D    (OFF_XC + 256u*256u*4u)      // dec_out row [256][256] f32
#define OFF_Y1   (OFF_D  + 256u*256u*4u)      // y1 [128][512] f32

typedef _Float16 half2_t __attribute__((ext_vector_type(2)));

__device__ __forceinline__ float fdot2f(uint32 w, uint32 h, float acc) {
#if __has_builtin(__builtin_amdgcn_fdot2)
  return __builtin_amdgcn_fdot2(__builtin_bit_cast(half2_t, w),
                                __builtin_bit_cast(half2_t, h), acc, false);
#else
  half2_t a = __builtin_bit_cast(half2_t, w);
  half2_t b = __builtin_bit_cast(half2_t, h);
  return acc + (float)a[0]*(float)b[0] + (float)a[1]*(float)b[1];
#endif
}

__device__ __forceinline__ uint32 pack_h2(float x, float y) {
  _Float16 hx = (_Float16)x, hy = (_Float16)y;
  u16 ux = __builtin_bit_cast(u16, hx);
  u16 uy = __builtin_bit_cast(u16, hy);
  return (uint32)ux | ((uint32)uy << 16);
}

// pack 8 consecutive f32 -> uint4 of 4 packed f16-pairs
__device__ __forceinline__ uint4 pk4(const float* __restrict__ p) {
  return uint4{pack_h2(p[0],p[1]), pack_h2(p[2],p[3]),
               pack_h2(p[4],p[5]), pack_h2(p[6],p[7])};
}

__device__ __forceinline__ float sigm(float x) { return 1.0f/(1.0f + expf(-x)); }

// ---- 32 named uint4 weight regs per lane = one full W_hh row (K=256, f16)
#define REP32(M) M(0) M(1) M(2) M(3) M(4) M(5) M(6) M(7) M(8) M(9) M(10) M(11) \
  M(12) M(13) M(14) M(15) M(16) M(17) M(18) M(19) M(20) M(21) M(22) M(23) \
  M(24) M(25) M(26) M(27) M(28) M(29) M(30) M(31)
#define WDECL(j) uint4 F##j{};
#define WLOAD(j) F##j = pk4(wrp + (j)*8);
#define WDOT(j)  { uint4 hp = h4[(j)]; \
  a0 = fdot2f(F##j.x, hp.x, a0); a1 = fdot2f(F##j.y, hp.y, a1); \
  a0 = fdot2f(F##j.z, hp.z, a0); a1 = fdot2f(F##j.w, hp.w, a1); }

// helper-WG input projection: xpo[t][o] = sum_k src[t][k]*wih[o][k] + bih[o]
// (+ bhh[o] folded for o<512, i.e. the r/z gates)
__device__ __forceinline__ void xp_gemm(
    const float* __restrict__ src, const float* __restrict__ wih,
    const float* __restrict__ bih, const float* __restrict__ bhh,
    float* __restrict__ xpo, int wgi, int tid, float (*XcL)[256])
{
  const int t0 = wgi * 4;
  for (int r = tid; r < 1024; r += NTH) XcL[r >> 8][r & 255] = src[t0 * 256 + r];
  __syncthreads();
  for (int o = tid; o < 768; o += NTH) {
    const float* wr = wih + o * 256;
    float a0 = 0.f, a1 = 0.f, a2 = 0.f, a3 = 0.f;
#pragma unroll 4
    for (int k = 0; k < 256; ++k) {
      float w = wr[k];
      a0 += w * XcL[0][k]; a1 += w * XcL[1][k];
      a2 += w * XcL[2][k]; a3 += w * XcL[3][k];
    }
    float b = bih[o] + ((o < 512) ? bhh[o] : 0.f);
    xpo[(t0+0)*768+o] = a0+b; xpo[(t0+1)*768+o] = a1+b;
    xpo[(t0+2)*768+o] = a2+b; xpo[(t0+3)*768+o] = a3+b;
  }
  __syncthreads();
}

extern "C" __global__ void __launch_bounds__(NTH, 1)
sed_kernel(const float* __restrict__ X,    const float* __restrict__ w1,
           const float* __restrict__ b1,   const float* __restrict__ w2,
           const float* __restrict__ b2,
           const float* __restrict__ ewih, const float* __restrict__ ewhh,
           const float* __restrict__ ebih, const float* __restrict__ ebhh,
           const float* __restrict__ dwih, const float* __restrict__ dwhh,
           const float* __restrict__ dbih, const float* __restrict__ dbhh,
           const float* __restrict__ fcw,  const float* __restrict__ fcb,
           float* __restrict__ out, unsigned char* __restrict__ ws)
{
  const int tid = threadIdx.x;
  const int wg  = blockIdx.x;
  uint32* bar_cnt = (uint32*)(ws);
  uint32* bar_rel = (uint32*)(ws + 128);
  uint32* mb_cnt  = (uint32*)(ws + OFF_MB1);
  uint32* mb_rel  = (uint32*)(ws + OFF_MB2);
  u16*   hb = (u16*)(ws + OFF_HB);            // 2 x 256 f16 h-exchange bufs
  float* xp = (float*)(ws + OFF_XP);
  float* Xc = (float*)(ws + OFF_XC);
  float* D  = (float*)(ws + OFF_D);
  float* y1 = (float*)(ws + OFF_Y1);

  __shared__ __align__(16) u16 h_lds[256];    // local copy of h (f16)
  __shared__ float part[192];                 // per-row dot results
  __shared__ float XcL[4][256];
  __shared__ float hv[256], red[256], abuf[256], cbuf[256], pbuf[256];
  __shared__ float lbuf[26*8], la[32];

  unsigned round_ = 0;
  auto gbar = [&]() {                         // full-grid barrier (68 WGs)
    __syncthreads();
    if (tid == 0) {
      unsigned old = __hip_atomic_fetch_add(bar_cnt, 1u, __ATOMIC_ACQ_REL,
                                            __HIP_MEMORY_SCOPE_AGENT);
      unsigned tgt = (round_ + 1u) * (unsigned)NWG;
      if (old + 1u == tgt)
        __hip_atomic_store(bar_rel, round_ + 1u, __ATOMIC_RELEASE,
                           __HIP_MEMORY_SCOPE_AGENT);
      while (__hip_atomic_load(bar_rel, __ATOMIC_ACQUIRE,
                               __HIP_MEMORY_SCOPE_AGENT) < round_ + 1u)
        __builtin_amdgcn_s_sleep(2);
    }
    round_ += 1u;
    __syncthreads();
  };

  unsigned m_round = 0;
  auto mbar = [&]() {                         // 4-WG GRU barrier (tight spin)
    __syncthreads();
    if (tid == 0) {
      unsigned old = __hip_atomic_fetch_add(mb_cnt, 1u, __ATOMIC_ACQ_REL,
                                            __HIP_MEMORY_SCOPE_AGENT);
      unsigned tgt = (m_round + 1u) * 4u;
      if (old + 1u == tgt)
        __hip_atomic_store(mb_rel, m_round + 1u, __ATOMIC_RELEASE,
                           __HIP_MEMORY_SCOPE_AGENT);
      while (__hip_atomic_load(mb_rel, __ATOMIC_ACQUIRE,
                               __HIP_MEMORY_SCOPE_AGENT) < m_round + 1u) {}
    }
    m_round += 1u;
    __syncthreads();
  };

  const int g = wg;            // GRU quarter id (valid when wg<4): units g*64..g*64+63
  // lane tid<192 owns one full W_hh row: gate=tid>>6 (0=r,1=z,2=n), unit j=tid&63
  REP32(WDECL)                 // 32 uint4 = 128 weight VGPRs
  float bn_ = 0.f, hreg = 0.f;

  auto loadW = [&](const float* __restrict__ whh, const float* __restrict__ bhh) {
    if (tid < 192) {
      const int gate = tid >> 6, j = tid & 63;
      const float* wrp = whh + (gate * 256 + g * 64 + j) * 256;
      REP32(WLOAD)
    }
    bn_ = (tid < 64) ? bhh[512 + g * 64 + tid] : 0.f;
  };

  // 256 sequential GRU cells, split across the 4 GRU WGs.
  auto cells = [&](const float* __restrict__ xpb, float* __restrict__ dst,
                   bool relu) {
    for (int t = 0; t < 256; ++t) {
      const float* xpt = xpb + t * 768;
      float xr = 0.f, xz = 0.f, xn = 0.f;
      if (tid < 64) {          // prefetch xp (b_ih + b_hh[r,z] already folded)
        xr = xpt[g * 64 + tid];
        xz = xpt[256 + g * 64 + tid];
        xn = xpt[512 + g * 64 + tid];
      }
      if (tid < 192) {         // 128 fdot2 against broadcast h
        const uint4* h4 = (const uint4*)h_lds;
        float a0 = 0.f, a1 = 0.f;
        REP32(WDOT)
        part[tid] = a0 + a1;
      }
      __syncthreads();
      if (tid < 64) {
        float r    = sigm(xr + part[tid]);
        float z    = sigm(xz + part[64 + tid]);
        float n    = tanhf(xn + r * (part[128 + tid] + bn_));
        float hnew = (1.0f - z) * n + z * hreg;
        hreg = hnew;
        hb[(t & 1) * 256 + g * 64 + tid] =
            __builtin_bit_cast(u16, (_Float16)hnew);       // publish h chunk
        dst[t * 256 + g * 64 + tid] = relu ? fmaxf(hnew, 0.0f) : hnew;
      }
      __threadfence();         // per-lane release of the h-chunk stores
      mbar();                  // all 4 quarters published
      if (tid < 32)            // gather full h (512 B) into local LDS
        ((uint4*)h_lds)[tid] = ((const uint4*)(hb + (t & 1) * 256))[tid];
      __syncthreads();
    }
  };

  // ---- P0a: y1[j][c] = w1[j]*x[c] + b1[j]   [128][512]
  for (int idx = wg * NTH + tid; idx < 128 * 512; idx += NWG * NTH) {
    int j = idx >> 9, c = idx & 511;
    y1[idx] = w1[j] * X[c] + b1[j];
  }
  gbar();

  // ---- P0b: seq[t][d] = y2[d][2t] (only even cols of y2 needed)
  for (int idx = wg * NTH + tid; idx < 256 * 256; idx += NWG * NTH) {
    int d = idx & 255, t = idx >> 8;
    const float* w2r = w2 + d * 128;
    float acc = b2[d];
#pragma unroll 4
    for (int j = 0; j < 128; ++j) acc += w2r[j] * y1[j * 512 + 2 * t];
    Xc[t * 256 + d] = acc;
  }
  gbar();

  // ---- P0c: helpers xp_enc = seq @ ewih^T (+biases); GRU WGs load enc W_hh
  if (wg < 4) loadW(ewhh, ebhh);
  else        xp_gemm(Xc, ewih, ebih, ebhh, xp, wg - 4, tid, XcL);
  gbar();

  // ---- P1: encoder (256 cells), writes relu(h) into Xc (=Xr)
  if (wg < 4) {
    if (tid < 128) ((uint32*)h_lds)[tid] = 0;
    hreg = 0.f;
    __syncthreads();
    cells(xp, Xc, true);
  }
  gbar();

  // ---- P2: helpers xp^0 = Xr @ dwih^T (+biases); GRU WGs load dec W_hh
  if (wg < 4) loadW(dwhh, dbhh);
  else        xp_gemm(Xc, dwih, dbih, dbhh, xp, wg - 4, tid, XcL);
  gbar();

  // ---- decoder: 256 outer rows
  for (int k = 0; k < 256; ++k) {
    // phase 1: GRU WGs run the 256 cells of row k (h carries across rows)
    if (wg < 4) cells(xp, D, false);
    gbar();

    // phase 2: helpers build xp^{k+1} from D; WG0 does attention + output row k
    if (wg == 0) {
      hv[tid] = D[255 * 256 + tid];              // h_new vector
      __syncthreads();
      // s_t = D[t,:]·h_new  (one lane per t)
      {
        const float* dr = D + tid * 256;
        float p = 0.f;
#pragma unroll 4
        for (int q = 0; q < 256; ++q) p += dr[q] * hv[q];
        pbuf[tid] = p; red[tid] = p;
      }
      __syncthreads();
      for (int st = 128; st > 0; st >>= 1) {
        if (tid < st) red[tid] = fmaxf(red[tid], red[tid + st]);
        __syncthreads();
      }
      float m = red[0];
      __syncthreads();
      { float e = expf(pbuf[tid] - m); abuf[tid] = e; red[tid] = e; }
      __syncthreads();
      for (int st = 128; st > 0; st >>= 1) {
        if (tid < st) red[tid] += red[tid + st];
        __syncthreads();
      }
      float inv = 1.0f / red[0];
      __syncthreads();
      abuf[tid] *= inv;
      __syncthreads();
      // c[i] = a[0]*D[0,i] + sum_{t=1..255} a[t-1]*D[t,i]
      {
        float acc = abuf[0] * D[tid];
        for (int t = 1; t < 256; ++t) acc += abuf[t - 1] * D[t * 256 + tid];
        cbuf[tid] = acc;
      }
      __syncthreads();
      // logits: fc_w @ [h_new, c] + fc_b  (26 outputs, 8 partials each)
      if (tid < 26 * 8) {
        int j = tid >> 3, sgm = tid & 7;
        const float* fr   = fcw + j * 512 + sgm * 64;
        const float* vsrc = (sgm < 4) ? (hv + sgm * 64) : (cbuf + (sgm - 4) * 64);
        float p = 0.f;
#pragma unroll 4
        for (int q = 0; q < 64; ++q) p += fr[q] * vsrc[q];
        lbuf[tid] = p;
      }
      __syncthreads();
      if (tid < 26) {
        float l = fcb[tid];
#pragma unroll
        for (int s = 0; s < 8; ++s) l += lbuf[tid * 8 + s];
        la[tid] = l;
      }
      __syncthreads();
      if (tid == 0) {
        float m2 = la[0];
        for (int j = 1; j < 26; ++j) m2 = fmaxf(m2, la[j]);
        float sm = 0.f;
        for (int j = 0; j < 26; ++j) { float e = expf(la[j] - m2); la[j] = e; sm += e; }
        float ii = 1.0f / sm;
        for (int j = 0; j < 26; ++j) la[j] *= ii;
      }
      __syncthreads();
      if (tid < 26) out[k * 26 + tid] = la[tid];
      __syncthreads();
    } else if (wg >= 4 && k < 255) {
      xp_gemm(D, dwih, dbih, dbhh, xp, wg - 4, tid, XcL);
    }
    gbar();
  }
}

extern "C" void kernel_launch(void* const* d_in, const int* in_sizes, int n_in,
                              void* d_out, int out_size, void* d_ws, size_t ws_size,
                              hipStream_t stream) {
  (void)in_sizes; (void)n_in; (void)out_size; (void)ws_size;
  // zero barrier counters + h-exchange region (ws is poisoned 0xAA pre-launch)
  hipMemsetAsync(d_ws, 0, 2048, stream);
  sed_kernel<<<NWG, NTH, 0, stream>>>(
      (const float*)d_in[0],  (const float*)d_in[1],  (const float*)d_in[2],
      (const float*)d_in[3],  (const float*)d_in[4],  (const float*)d_in[5],
      (const float*)d_in[6],  (const float*)d_in[7],  (const float*)d_in[8],
      (const float*)d_in[9],  (const float*)d_in[10], (const float*)d_in[11],
      (const float*)d_in[12], (const float*)d_in[13], (const float*)d_in[14],
      (float*)d_out, (unsigned char*)d_ws);
}